// Round 6
// baseline (291.236 us; speedup 1.0000x reference)
//
#include <hip/hip_runtime.h>
#include <hip/hip_bf16.h>

typedef __bf16 bf16x8 __attribute__((ext_vector_type(8)));
typedef __bf16 bf16x4 __attribute__((ext_vector_type(4)));
typedef float  f32x4  __attribute__((ext_vector_type(4)));

namespace {
constexpr int P       = 20001;   // MOVIES + 1 (padding row)
constexpr int NT_TILE = 1251;    // ceil(P/16)
constexpr int PROWS   = NT_TILE * 16;  // 20016 padded rows
constexpr int NGENRES = 20;
constexpr int NTAGS   = 1000;
constexpr int NGTAGS  = 1128;
constexpr int NB      = 1024;
constexpr int NH      = 50;
constexpr int PHID    = 256;
constexpr int OD      = 128;
constexpr int EG = 8, ET = 16, EGT = 16, EM = 32, EY = 8, EUG = 32, ETS = 4;
constexpr int PAD  = 20000;
constexpr int SAW  = 2184;   // combined A stride (bf16): 1024 tag + 1152 genome + 8 pad
constexpr int GOFF = 1024;   // genome col base in A buffer
constexpr int SC   = 104;    // s_cat stride bf16 (96 used)
constexpr int SH   = 264;    // hidden stride bf16 (256 used)
constexpr int UC   = 192;    // user-cat padded width (180 + 12 zeros)
constexpr int UCS  = 200;    // mlp LDS stride for Ucat tile
constexpr int KC_TAG = 32, KC_GEN = 36;
constexpr int KC_IP1 = 3,  NT_IP1 = 16;   // K=96(80 real), N=256
constexpr int KC_IP2 = 8,  NT_IP2 = 8;    // K=256, N=128
constexpr int KC_UP1 = 6,  NT_UP1 = 16;   // K=192(180 real), N=256
constexpr int KC_UP2 = 8,  NT_UP2 = 8;    // K=256, N=128
}

static __device__ __forceinline__ f32x4 mfma16(bf16x8 a, bf16x8 b, f32x4 c) {
  return __builtin_amdgcn_mfma_f32_16x16x32_bf16(a, b, c, 0, 0, 0);
}

// ---------------------------------------------------------------------------
// Setup: pre-swizzle all MFMA B-operands into fragment layout:
// frag(kc,nt)[lane][j] = W[kc*32 + (lane>>4)*8 + j][nt*16 + (lane&15)], bf16,
// zero past K. One 512-thr block per fragment; 340 fragments.
// ---------------------------------------------------------------------------
__global__ __launch_bounds__(512) void setup_wf_kernel(
    const float* __restrict__ w_tag, const float* __restrict__ w_genome,
    const float* __restrict__ w_ip1, const float* __restrict__ w_ip2,
    const float* __restrict__ w_up1, const float* __restrict__ w_up2,
    __bf16* __restrict__ Wtf, __bf16* __restrict__ Wgf,
    __bf16* __restrict__ Wip1f, __bf16* __restrict__ Wip2f,
    __bf16* __restrict__ Wup1f, __bf16* __restrict__ Wup2f)
{
  const int b = blockIdx.x, t = threadIdx.x;
  const int l = t >> 3, j = t & 7;
  const int krow = (l >> 4) * 8 + j, l15 = l & 15;
  const float* src; __bf16* dst; int K, N, kc, nt;
  if (b < 32)        { src = w_tag;    dst = Wtf   + (long)b * 512;       K = NTAGS;  N = 16;  kc = b;      nt = 0; }
  else if (b < 68)   { int i = b - 32;  src = w_genome; dst = Wgf   + (long)i * 512; K = NGTAGS; N = 16;  kc = i;      nt = 0; }
  else if (b < 116)  { int i = b - 68;  src = w_ip1;    dst = Wip1f + (long)i * 512; K = 80;     N = 256; kc = i / 16; nt = i % 16; }
  else if (b < 180)  { int i = b - 116; src = w_ip2;    dst = Wip2f + (long)i * 512; K = 256;    N = 128; kc = i / 8;  nt = i % 8; }
  else if (b < 276)  { int i = b - 180; src = w_up1;    dst = Wup1f + (long)i * 512; K = 180;    N = 256; kc = i / 16; nt = i % 16; }
  else               { int i = b - 276; src = w_up2;    dst = Wup2f + (long)i * 512; K = 256;    N = 128; kc = i / 8;  nt = i % 8; }
  const int k = kc * 32 + krow, n = nt * 16 + l15;
  float v = (k < K) ? src[(long)k * N + n] : 0.f;
  dst[t] = (__bf16)v;
}

// ---------------------------------------------------------------------------
// Tower: one block = one 16-movie tile. SINGLE load burst (tag+genome) ->
// one barrier -> both MFMA passes -> parallel epilogues -> smalls -> ip1/ip2.
// Emits T (fp32, for final dot), Tb (bf16, pool), GTb (bf16, pool).
// ---------------------------------------------------------------------------
__global__ __launch_bounds__(256) void tower_kernel(
    const float* __restrict__ tag_ctx, const float* __restrict__ genome_ctx,
    const float* __restrict__ genre_ctx, const int* __restrict__ year_ctx,
    const float* __restrict__ item_emb, const float* __restrict__ year_tab,
    const float* __restrict__ w_genre, const float* __restrict__ b_genre,
    const float* __restrict__ b_tag,   const float* __restrict__ b_genome,
    const float* __restrict__ w_item,  const float* __restrict__ b_item,
    const float* __restrict__ w_year,  const float* __restrict__ b_year,
    const float* __restrict__ b_ip1,   const float* __restrict__ b_ip2,
    const __bf16* __restrict__ Wtf,   const __bf16* __restrict__ Wgf,
    const __bf16* __restrict__ Wip1f, const __bf16* __restrict__ Wip2f,
    float* __restrict__ T, __bf16* __restrict__ Tb, __bf16* __restrict__ GTb)
{
  union ShU { __bf16 a[16][SAW]; __bf16 h[16][SH]; };   // 68.3 KB / 8.3 KB
  __shared__ __align__(16) ShU u;
  __shared__ __align__(16) __bf16 s_cat[16][SC];        // 3.3 KB
  __shared__ __align__(16) f32x4  s_redT[3][64];        // 3 KB
  __shared__ __align__(16) f32x4  s_redG[3][64];        // 3 KB

  const int t = threadIdx.x, tile = blockIdx.x;
  const int wave = t >> 6, lane = t & 63, l15 = lane & 15, quad = lane >> 4;
  const int r = t >> 4, c16 = t & 15;                   // staging coords
  const long rid = min(tile * 16 + r, P - 1);

  // ===== P0: stage ALL ctx rows in one burst (coalesced fp32 -> bf16) =====
  {
    const float* rowT = tag_ctx + rid * NTAGS;
    #pragma unroll
    for (int i = 0; i < 16; ++i) {
      int f = c16 + i * 16;                              // float4 idx, 250 real
      if (f < 250) {
        float4 v = *(const float4*)(rowT + f * 4);
        *(bf16x4*)&u.a[r][f * 4] =
            (bf16x4){(__bf16)v.x, (__bf16)v.y, (__bf16)v.z, (__bf16)v.w};
      }
    }
    const float* rowG = genome_ctx + rid * NGTAGS;
    #pragma unroll
    for (int i = 0; i < 18; ++i) {
      int f = c16 + i * 16;                              // 282 real float4s
      if (f < 282) {
        float4 v = *(const float4*)(rowG + f * 4);
        *(bf16x4*)&u.a[r][GOFF + f * 4] =
            (bf16x4){(__bf16)v.x, (__bf16)v.y, (__bf16)v.z, (__bf16)v.w};
      }
    }
    if (c16 < 6) {
      const bf16x4 z = {(__bf16)0.f, (__bf16)0.f, (__bf16)0.f, (__bf16)0.f};
      *(bf16x4*)&u.a[r][NTAGS + c16 * 4] = z;            // 1000..1023
      *(bf16x4*)&u.a[r][GOFF + NGTAGS + c16 * 4] = z;    // 1128..1151
    }
  }
  __syncthreads();

  // ===== P1: tag MFMA (wave owns kc wave*8..+7) then genome (wave*9..+8) ====
  f32x4 accT = {0.f, 0.f, 0.f, 0.f};
  #pragma unroll
  for (int kc = 0; kc < 8; ++kc) {
    const int kcg = wave * 8 + kc;
    bf16x8 a  = *(const bf16x8*)&u.a[l15][kcg * 32 + quad * 8];
    bf16x8 bb = *(const bf16x8*)(Wtf + ((long)kcg * 64 + lane) * 8);
    accT = mfma16(a, bb, accT);
  }
  f32x4 accG = {0.f, 0.f, 0.f, 0.f};
  #pragma unroll
  for (int kc = 0; kc < 9; ++kc) {
    const int kcg = wave * 9 + kc;
    bf16x8 a  = *(const bf16x8*)&u.a[l15][GOFF + kcg * 32 + quad * 8];
    bf16x8 bb = *(const bf16x8*)(Wgf + ((long)kcg * 64 + lane) * 8);
    accG = mfma16(a, bb, accG);
  }
  if (wave != 0) s_redT[wave - 1][lane] = accT;
  if (wave != 1) s_redG[wave == 0 ? 0 : wave - 1][lane] = accG;
  __syncthreads();

  // ===== P2: parallel epilogues (wave0 tag, wave1 genome) + small towers ====
  if (wave == 0) {
    accT += s_redT[0][lane]; accT += s_redT[1][lane]; accT += s_redT[2][lane];
    const float bt = b_tag[l15];
    #pragma unroll
    for (int r2 = 0; r2 < 4; ++r2)
      s_cat[quad * 4 + r2][EG + l15] = (__bf16)tanhf(accT[r2] + bt);
  } else if (wave == 1) {
    accG += s_redG[0][lane]; accG += s_redG[1][lane]; accG += s_redG[2][lane];
    const float bg = b_genome[l15];
    #pragma unroll
    for (int r2 = 0; r2 < 4; ++r2) {
      int m = quad * 4 + r2;
      float v = tanhf(accG[r2] + bg);
      s_cat[m][EG + ET + l15] = (__bf16)v;
      GTb[(long)(tile * 16 + m) * EGT + l15] = (__bf16)v;
    }
  }
  {
    const int m = r, j = c16;
    const long id = rid;
    if (j < 8) {   // genre tower (8 cols) + zero K-pad 80..95
      const float* rg = genre_ctx + id * NGENRES;
      float a = b_genre[j];
      #pragma unroll
      for (int k = 0; k < NGENRES; ++k) a = fmaf(rg[k], w_genre[k * EG + j], a);
      s_cat[m][j] = (__bf16)tanhf(a);
      s_cat[m][80 + j] = (__bf16)0.f;
      s_cat[m][88 + j] = (__bf16)0.f;
    } else {       // year tower (8 cols)
      const int jj = j - 8;
      const int yr = year_ctx[id];
      float a = b_year[jj];
      #pragma unroll
      for (int k = 0; k < EY; ++k)
        a = fmaf(year_tab[yr * EY + k], w_year[k * EY + jj], a);
      s_cat[m][72 + jj] = (__bf16)tanhf(a);    // 72 = EG+ET+EGT+EM
    }
    const float* e = item_emb + id * EM;       // item tower: 2 cols/thread
    float a0 = b_item[2 * j], a1 = b_item[2 * j + 1];
    #pragma unroll 8
    for (int k = 0; k < EM; ++k) {
      float ev = e[k];
      a0 = fmaf(ev, w_item[k * EM + 2 * j], a0);
      a1 = fmaf(ev, w_item[k * EM + 2 * j + 1], a1);
    }
    s_cat[m][40 + 2 * j]     = (__bf16)tanhf(a0);   // 40 = EG+ET+EGT
    s_cat[m][40 + 2 * j + 1] = (__bf16)tanhf(a1);
  }
  __syncthreads();

  // ===== P3: ip1 MFMA [16,96]@[96,256] -> relu -> u.h =====
  {
    bf16x8 af[KC_IP1];
    #pragma unroll
    for (int kc = 0; kc < KC_IP1; ++kc)
      af[kc] = *(const bf16x8*)&s_cat[l15][kc * 32 + quad * 8];
    #pragma unroll
    for (int nt = 0; nt < 4; ++nt) {
      const int n = wave * 64 + nt * 16 + l15;
      const float bb = b_ip1[n];
      f32x4 acc = {bb, bb, bb, bb};
      #pragma unroll
      for (int kc = 0; kc < KC_IP1; ++kc) {
        bf16x8 bfr = *(const bf16x8*)(Wip1f + ((long)(kc * NT_IP1 + wave * 4 + nt) * 64 + lane) * 8);
        acc = mfma16(af[kc], bfr, acc);
      }
      #pragma unroll
      for (int r2 = 0; r2 < 4; ++r2)
        u.h[quad * 4 + r2][n] = (__bf16)fmaxf(acc[r2], 0.f);
    }
  }
  __syncthreads();

  // ===== P4: ip2 MFMA [16,256]@[256,128] -> T (fp32) + Tb (bf16) =====
  {
    bf16x8 af[KC_IP2];
    #pragma unroll
    for (int kc = 0; kc < KC_IP2; ++kc)
      af[kc] = *(const bf16x8*)&u.h[l15][kc * 32 + quad * 8];
    #pragma unroll
    for (int nt = 0; nt < 2; ++nt) {
      const int n = wave * 32 + nt * 16 + l15;
      const float bb = b_ip2[n];
      f32x4 acc = {bb, bb, bb, bb};
      #pragma unroll
      for (int kc = 0; kc < KC_IP2; ++kc) {
        bf16x8 bfr = *(const bf16x8*)(Wip2f + ((long)(kc * NT_IP2 + wave * 2 + nt) * 64 + lane) * 8);
        acc = mfma16(af[kc], bfr, acc);
      }
      #pragma unroll
      for (int r2 = 0; r2 < 4; ++r2) {
        const long row = tile * 16 + quad * 4 + r2;
        T [row * OD + n] = acc[r2];
        Tb[row * OD + n] = (__bf16)acc[r2];
      }
    }
  }
}

// ---------------------------------------------------------------------------
// Pool: per-user pooling from bf16 tables -> Ucat[1024][192] bf16.
// ---------------------------------------------------------------------------
__global__ __launch_bounds__(256) void user_pool_kernel(
    const float* __restrict__ ugc, const int* __restrict__ hist,
    const float* __restrict__ ratings, const int* __restrict__ tstamps,
    const float* __restrict__ ts_tab,
    const float* __restrict__ w_ugenre, const float* __restrict__ b_ugenre,
    const float* __restrict__ w_ts, const float* __restrict__ b_ts,
    const __bf16* __restrict__ Tb, const __bf16* __restrict__ GTb,
    __bf16* __restrict__ Ucat)
{
  __shared__ float s_w[64];
  __shared__ int   s_ids[64];
  __shared__ float s_part[2][OD];
  __shared__ float s_gp[8][EGT];
  __shared__ float s_inv;

  const int b = blockIdx.x, t = threadIdx.x;

  if (t < 64) {
    int id = PAD; float w = 0.f;
    if (t < NH) {
      id = hist[b * NH + t];
      float r = ratings[b * NH + t];
      w = (id != PAD) ? r : 0.f;
    }
    s_ids[t] = id; s_w[t] = w;
    float s = fabsf(w);
    #pragma unroll
    for (int off = 32; off; off >>= 1) s += __shfl_xor(s, off, 64);
    if (t == 0) s_inv = 1.f / fmaxf(s, 1e-6f);
  }
  __syncthreads();
  const float inv = s_inv;

  {  // item pool partials: 2 x 25 gathers per column (128B contig per wave)
    const int c = t & (OD - 1), part = t >> 7;
    float acc = 0.f;
    #pragma unroll
    for (int i = 0; i < 25; ++i) {
      const int h = part * 25 + i;
      acc = fmaf(s_w[h], (float)Tb[(long)s_ids[h] * OD + c], acc);
    }
    s_part[part][c] = acc;
  }
  __syncthreads();
  if (t < OD) {
    Ucat[(long)b * UC + t] = (__bf16)((s_part[0][t] + s_part[1][t]) * inv);
  } else {
    const int uu = t - 128, col = uu & 15, part = uu >> 4;  // 8 parts x 7 h
    float acc = 0.f;
    #pragma unroll
    for (int i = 0; i < 7; ++i) {
      const int h = part * 7 + i;
      if (h < NH) acc = fmaf(s_w[h], (float)GTb[(long)s_ids[h] * EGT + col], acc);
    }
    s_gp[part][col] = acc;
  }
  __syncthreads();
  if (t < EGT) {
    float acc = 0.f;
    #pragma unroll
    for (int p = 0; p < 8; ++p) acc += s_gp[p][t];
    Ucat[(long)b * UC + OD + t] = (__bf16)(acc * inv);
  } else if (t >= 32 && t < 64) {
    const int j = t - 32;
    float a = b_ugenre[j];
    #pragma unroll
    for (int k = 0; k < NGENRES; ++k)
      a = fmaf(ugc[b * NGENRES + k], w_ugenre[k * EUG + j], a);
    Ucat[(long)b * UC + 144 + j] = (__bf16)tanhf(a);     // 128+16
  } else if (t >= 64 && t < 64 + ETS) {
    const int j = t - 64;
    const int ts = tstamps[b];
    float a = b_ts[j];
    #pragma unroll
    for (int k = 0; k < ETS; ++k)
      a = fmaf(ts_tab[ts * ETS + k], w_ts[k * ETS + j], a);
    Ucat[(long)b * UC + 176 + j] = (__bf16)tanhf(a);     // 128+16+32
  } else if (t >= 68 && t < 80) {
    Ucat[(long)b * UC + 180 + (t - 68)] = (__bf16)0.f;   // zero pad
  }
}

// ---------------------------------------------------------------------------
// MLP: user MLP via MFMA + final dot. 64 blocks x 16 users.
// ---------------------------------------------------------------------------
__global__ __launch_bounds__(256) void user_mlp_kernel(
    const int* __restrict__ target,
    const float* __restrict__ b_up1, const float* __restrict__ b_up2,
    const __bf16* __restrict__ Wup1f, const __bf16* __restrict__ Wup2f,
    const __bf16* __restrict__ Ucat, const float* __restrict__ T,
    float* __restrict__ out)
{
  __shared__ __align__(16) __bf16 s_u[16][UCS];   // 6.4 KB
  __shared__ __align__(16) __bf16 s_h[16][SH];    // 8.4 KB
  __shared__ __align__(16) float  s_e[16][132];   // 8.4 KB

  const int t = threadIdx.x, blk = blockIdx.x;
  const int wave = t >> 6, lane = t & 63, l15 = lane & 15, quad = lane >> 4;
  const int u0 = blk * 16;

  {  // stage Ucat tile
    const int uu = t >> 4, s = t & 15;
    const __bf16* src = Ucat + (long)(u0 + uu) * UC;
    *(bf16x8*)&s_u[uu][s * 8] = *(const bf16x8*)(src + s * 8);
    if (s < 8)
      *(bf16x8*)&s_u[uu][(s + 16) * 8] = *(const bf16x8*)(src + (s + 16) * 8);
  }
  __syncthreads();

  // ---- up1: [16,192]@[192,256] -> relu -> s_h ----
  {
    bf16x8 af[KC_UP1];
    #pragma unroll
    for (int kc = 0; kc < KC_UP1; ++kc)
      af[kc] = *(const bf16x8*)&s_u[l15][kc * 32 + quad * 8];
    #pragma unroll
    for (int nt = 0; nt < 4; ++nt) {
      const int n = wave * 64 + nt * 16 + l15;
      const float bb = b_up1[n];
      f32x4 acc = {bb, bb, bb, bb};
      #pragma unroll
      for (int kc = 0; kc < KC_UP1; ++kc) {
        bf16x8 bfr = *(const bf16x8*)(Wup1f + ((long)(kc * NT_UP1 + wave * 4 + nt) * 64 + lane) * 8);
        acc = mfma16(af[kc], bfr, acc);
      }
      #pragma unroll
      for (int r2 = 0; r2 < 4; ++r2)
        s_h[quad * 4 + r2][n] = (__bf16)fmaxf(acc[r2], 0.f);
    }
  }
  __syncthreads();

  // ---- up2: [16,256]@[256,128] -> s_e fp32 ----
  {
    bf16x8 af[KC_UP2];
    #pragma unroll
    for (int kc = 0; kc < KC_UP2; ++kc)
      af[kc] = *(const bf16x8*)&s_h[l15][kc * 32 + quad * 8];
    #pragma unroll
    for (int nt = 0; nt < 2; ++nt) {
      const int n = wave * 32 + nt * 16 + l15;
      const float bb = b_up2[n];
      f32x4 acc = {bb, bb, bb, bb};
      #pragma unroll
      for (int kc = 0; kc < KC_UP2; ++kc) {
        bf16x8 bfr = *(const bf16x8*)(Wup2f + ((long)(kc * NT_UP2 + wave * 2 + nt) * 64 + lane) * 8);
        acc = mfma16(af[kc], bfr, acc);
      }
      #pragma unroll
      for (int r2 = 0; r2 < 4; ++r2)
        s_e[quad * 4 + r2][n] = acc[r2];
    }
  }
  __syncthreads();

  // ---- dot(user, T[target]): 8 threads per user ----
  if (t < 128) {
    const int uu = t >> 3, q = t & 7;
    const int tgt = target[u0 + uu];
    const float* trow = T + (long)tgt * OD + q * 16;
    float s = 0.f;
    #pragma unroll
    for (int i = 0; i < 4; ++i) {
      float4 v = *(const float4*)(trow + i * 4);
      f32x4 e = *(const f32x4*)&s_e[uu][q * 16 + i * 4];
      s += v.x * e[0] + v.y * e[1] + v.z * e[2] + v.w * e[3];
    }
    s += __shfl_down(s, 1, 64);
    s += __shfl_down(s, 2, 64);
    s += __shfl_down(s, 4, 64);
    if (q == 0) out[u0 + uu] = s;
  }
}

// ---------------------------------------------------------------------------
extern "C" void kernel_launch(void* const* d_in, const int* in_sizes, int n_in,
                              void* d_out, int out_size, void* d_ws, size_t ws_size,
                              hipStream_t stream) {
  const float* ugc      = (const float*)d_in[0];
  const int*   hist     = (const int*)  d_in[1];
  const float* ratings  = (const float*)d_in[2];
  const int*   tstamps  = (const int*)  d_in[3];
  const int*   target   = (const int*)  d_in[4];
  const float* genome   = (const float*)d_in[5];
  const float* genrec   = (const float*)d_in[6];
  const float* tagc     = (const float*)d_in[7];
  const int*   yearc    = (const int*)  d_in[8];
  const float* item_emb = (const float*)d_in[9];
  const float* year_tab = (const float*)d_in[10];
  const float* ts_tab   = (const float*)d_in[11];
  const float* w_item   = (const float*)d_in[12];
  const float* b_item   = (const float*)d_in[13];
  const float* w_genre  = (const float*)d_in[14];
  const float* b_genre  = (const float*)d_in[15];
  const float* w_tag    = (const float*)d_in[16];
  const float* b_tag    = (const float*)d_in[17];
  const float* w_genome = (const float*)d_in[18];
  const float* b_genome = (const float*)d_in[19];
  const float* w_year   = (const float*)d_in[20];
  const float* b_year   = (const float*)d_in[21];
  const float* w_ugenre = (const float*)d_in[22];
  const float* b_ugenre = (const float*)d_in[23];
  const float* w_ts     = (const float*)d_in[24];
  const float* b_ts     = (const float*)d_in[25];
  const float* w_up1    = (const float*)d_in[26];
  const float* b_up1    = (const float*)d_in[27];
  const float* w_up2    = (const float*)d_in[28];
  const float* b_up2    = (const float*)d_in[29];
  const float* w_ip1    = (const float*)d_in[30];
  const float* b_ip1    = (const float*)d_in[31];
  const float* w_ip2    = (const float*)d_in[32];
  const float* b_ip2    = (const float*)d_in[33];

  char* ws = (char*)d_ws;
  size_t off = 0;
  float*  T     = (float*) (ws + off); off += (size_t)PROWS * OD * 4;   // 10.25 MB
  __bf16* Tb    = (__bf16*)(ws + off); off += (size_t)PROWS * OD * 2;   // 5.12 MB
  __bf16* GTb   = (__bf16*)(ws + off); off += (size_t)PROWS * EGT * 2;  // 0.64 MB
  __bf16* Ucat  = (__bf16*)(ws + off); off += (size_t)NB * UC * 2;      // 0.39 MB
  __bf16* Wtf   = (__bf16*)(ws + off); off += (size_t)KC_TAG * 512 * 2;
  __bf16* Wgf   = (__bf16*)(ws + off); off += (size_t)KC_GEN * 512 * 2;
  __bf16* Wip1f = (__bf16*)(ws + off); off += (size_t)KC_IP1 * NT_IP1 * 512 * 2;
  __bf16* Wip2f = (__bf16*)(ws + off); off += (size_t)KC_IP2 * NT_IP2 * 512 * 2;
  __bf16* Wup1f = (__bf16*)(ws + off); off += (size_t)KC_UP1 * NT_UP1 * 512 * 2;
  __bf16* Wup2f = (__bf16*)(ws + off); off += (size_t)KC_UP2 * NT_UP2 * 512 * 2;

  setup_wf_kernel<<<dim3(340), dim3(512), 0, stream>>>(
      w_tag, w_genome, w_ip1, w_ip2, w_up1, w_up2,
      Wtf, Wgf, Wip1f, Wip2f, Wup1f, Wup2f);

  tower_kernel<<<dim3(NT_TILE), dim3(256), 0, stream>>>(
      tagc, genome, genrec, yearc, item_emb, year_tab,
      w_genre, b_genre, b_tag, b_genome, w_item, b_item, w_year, b_year,
      b_ip1, b_ip2, Wtf, Wgf, Wip1f, Wip2f, T, Tb, GTb);

  user_pool_kernel<<<dim3(NB), dim3(256), 0, stream>>>(
      ugc, hist, ratings, tstamps, ts_tab,
      w_ugenre, b_ugenre, w_ts, b_ts, Tb, GTb, Ucat);

  user_mlp_kernel<<<dim3(NB / 16), dim3(256), 0, stream>>>(
      target, b_up1, b_up2, Wup1f, Wup2f, Ucat, T, (float*)d_out);
}